// Round 1
// baseline (675.977 us; speedup 1.0000x reference)
//
#include <hip/hip_runtime.h>

// Pipeline:
//   g = h @ W1                      (node GEMM, replaces per-edge GEMM)
//   att[e] = sigmoid(relu(relu(g[src]-g[dst]+b1) . W2 + b2))
//   denom[n] = sum_{e: src[e]==n} att[e]
//   out[d] += (att[e]/denom[src[e]]) * h[src[e]]

__global__ __launch_bounds__(256) void k_gemm(const float* __restrict__ h,
                                              const float* __restrict__ W1,
                                              float* __restrict__ g, int n_nodes) {
  __shared__ float w1s[128 * 128];     // 64 KiB: W1 staged once per block
  __shared__ float rowbuf[4][128];     // per-wave h-row broadcast buffer
  int tid = threadIdx.x;
  for (int i = tid * 4; i < 128 * 128; i += 256 * 4) {
    *(float4*)&w1s[i] = *(const float4*)&W1[i];
  }
  __syncthreads();
  int wave = tid >> 6, lane = tid & 63;
  int gwaves = gridDim.x * 4;
  for (int n = blockIdx.x * 4 + wave; n < n_nodes; n += gwaves) {
    float2 hv = *(const float2*)&h[(size_t)n * 128 + lane * 2];
    rowbuf[wave][lane * 2] = hv.x;
    rowbuf[wave][lane * 2 + 1] = hv.y;
    float acc0 = 0.f, acc1 = 0.f;
    // w1s[k*128+lane]: bank = lane%32 -> 2-way across wave64 = free
    #pragma unroll
    for (int k = 0; k < 128; k += 4) {
      float4 hk = *(float4*)&rowbuf[wave][k];
      acc0 += hk.x * w1s[(k + 0) * 128 + lane];
      acc1 += hk.x * w1s[(k + 0) * 128 + lane + 64];
      acc0 += hk.y * w1s[(k + 1) * 128 + lane];
      acc1 += hk.y * w1s[(k + 1) * 128 + lane + 64];
      acc0 += hk.z * w1s[(k + 2) * 128 + lane];
      acc1 += hk.z * w1s[(k + 2) * 128 + lane + 64];
      acc0 += hk.w * w1s[(k + 3) * 128 + lane];
      acc1 += hk.w * w1s[(k + 3) * 128 + lane + 64];
    }
    g[(size_t)n * 128 + lane] = acc0;
    g[(size_t)n * 128 + lane + 64] = acc1;
  }
}

__global__ __launch_bounds__(256) void k_att(const float* __restrict__ g,
                                             const int* __restrict__ src,
                                             const int* __restrict__ dst,
                                             const float* __restrict__ b1,
                                             const float* __restrict__ W2,
                                             const float* __restrict__ b2,
                                             float* __restrict__ att,
                                             float* __restrict__ denom,
                                             int n_edges) {
  int lane = threadIdx.x & 63;
  int wave = (int)((blockIdx.x * blockDim.x + threadIdx.x) >> 6);
  int gwaves = (int)((gridDim.x * blockDim.x) >> 6);
  float2 b1v = *(const float2*)&b1[lane * 2];
  float2 w2v = *(const float2*)&W2[lane * 2];
  float b2v = b2[0];
  for (int e = wave; e < n_edges; e += gwaves) {
    int s = src[e], d = dst[e];
    float2 gs = *(const float2*)&g[(size_t)s * 128 + lane * 2];
    float2 gd = *(const float2*)&g[(size_t)d * 128 + lane * 2];
    float t0 = fmaxf(gs.x - gd.x + b1v.x, 0.f);
    float t1 = fmaxf(gs.y - gd.y + b1v.y, 0.f);
    float acc = t0 * w2v.x + t1 * w2v.y;
    #pragma unroll
    for (int off = 1; off < 64; off <<= 1) acc += __shfl_xor(acc, off);
    if (lane == 0) {
      float a = fmaxf(acc + b2v, 0.f);
      a = 1.f / (1.f + __expf(-a));
      att[e] = a;
      atomicAdd(&denom[s], a);
    }
  }
}

__global__ __launch_bounds__(256) void k_scatter(const float* __restrict__ h,
                                                 const int* __restrict__ src,
                                                 const int* __restrict__ dst,
                                                 const float* __restrict__ att,
                                                 const float* __restrict__ denom,
                                                 float* __restrict__ out,
                                                 int n_edges) {
  int lane = threadIdx.x & 63;
  int wave = (int)((blockIdx.x * blockDim.x + threadIdx.x) >> 6);
  int gwaves = (int)((gridDim.x * blockDim.x) >> 6);
  for (int e = wave; e < n_edges; e += gwaves) {
    int s = src[e], d = dst[e];
    float w = att[e] / denom[s];
    float2 hv = *(const float2*)&h[(size_t)s * 128 + lane * 2];
    atomicAdd(&out[(size_t)d * 128 + lane * 2], w * hv.x);
    atomicAdd(&out[(size_t)d * 128 + lane * 2 + 1], w * hv.y);
  }
}

extern "C" void kernel_launch(void* const* d_in, const int* in_sizes, int n_in,
                              void* d_out, int out_size, void* d_ws, size_t ws_size,
                              hipStream_t stream) {
  const float* h   = (const float*)d_in[0];
  const int*   src = (const int*)d_in[1];
  const int*   dst = (const int*)d_in[2];
  const float* W1  = (const float*)d_in[3];
  const float* b1  = (const float*)d_in[4];
  const float* W2  = (const float*)d_in[5];
  const float* b2  = (const float*)d_in[6];
  float* out = (float*)d_out;

  int n_nodes = in_sizes[0] / 128;
  int n_edges = in_sizes[1];

  char* ws = (char*)d_ws;
  float* g     = (float*)ws;                                   // n_nodes*128
  float* att   = (float*)(ws + (size_t)n_nodes * 128 * 4);     // n_edges
  float* denom = att + n_edges;                                // n_nodes

  hipMemsetAsync(out, 0, (size_t)out_size * sizeof(float), stream);
  hipMemsetAsync(denom, 0, (size_t)n_nodes * sizeof(float), stream);

  k_gemm<<<1024, 256, 0, stream>>>(h, W1, g, n_nodes);
  k_att<<<4096, 256, 0, stream>>>(g, src, dst, b1, W2, b2, att, denom, n_edges);
  k_scatter<<<4096, 256, 0, stream>>>(h, src, dst, att, denom, out, n_edges);
}

// Round 2
// 415.759 us; speedup vs baseline: 1.6259x; 1.6259x over previous
//
#include <hip/hip_runtime.h>

// Pipeline:
//   g = h @ W1                      (node GEMM, replaces per-edge GEMM)
//   att[e] = sigmoid(relu(relu(g[src]-g[dst]+b1) . W2 + b2))
//   denom[n] = sum_{e: src[e]==n} att[e]
//   CSR by dst:  hist -> scan -> fill  (bucket[] holds edge ids per dst)
//   out[d] = sum_{e in bucket[d]} (att[e]/denom[src[e]]) * h[src[e]]   (pull, no atomics)

__global__ __launch_bounds__(256) void k_gemm(const float* __restrict__ h,
                                              const float* __restrict__ W1,
                                              float* __restrict__ g, int n_nodes) {
  __shared__ float w1s[128 * 128];     // 64 KiB: W1 staged once per block
  __shared__ float rowbuf[4][128];     // per-wave h-row broadcast buffer
  int tid = threadIdx.x;
  for (int i = tid * 4; i < 128 * 128; i += 256 * 4) {
    *(float4*)&w1s[i] = *(const float4*)&W1[i];
  }
  __syncthreads();
  int wave = tid >> 6, lane = tid & 63;
  int gwaves = gridDim.x * 4;
  for (int n = blockIdx.x * 4 + wave; n < n_nodes; n += gwaves) {
    float2 hv = *(const float2*)&h[(size_t)n * 128 + lane * 2];
    rowbuf[wave][lane * 2] = hv.x;
    rowbuf[wave][lane * 2 + 1] = hv.y;
    float acc0 = 0.f, acc1 = 0.f;
    #pragma unroll
    for (int k = 0; k < 128; k += 4) {
      float4 hk = *(float4*)&rowbuf[wave][k];
      acc0 += hk.x * w1s[(k + 0) * 128 + lane];
      acc1 += hk.x * w1s[(k + 0) * 128 + lane + 64];
      acc0 += hk.y * w1s[(k + 1) * 128 + lane];
      acc1 += hk.y * w1s[(k + 1) * 128 + lane + 64];
      acc0 += hk.z * w1s[(k + 2) * 128 + lane];
      acc1 += hk.z * w1s[(k + 2) * 128 + lane + 64];
      acc0 += hk.w * w1s[(k + 3) * 128 + lane];
      acc1 += hk.w * w1s[(k + 3) * 128 + lane + 64];
    }
    g[(size_t)n * 128 + lane] = acc0;
    g[(size_t)n * 128 + lane + 64] = acc1;
  }
}

__global__ __launch_bounds__(256) void k_att(const float* __restrict__ g,
                                             const int* __restrict__ src,
                                             const int* __restrict__ dst,
                                             const float* __restrict__ b1,
                                             const float* __restrict__ W2,
                                             const float* __restrict__ b2,
                                             float* __restrict__ att,
                                             float* __restrict__ denom,
                                             int n_edges) {
  int lane = threadIdx.x & 63;
  int wave = (int)((blockIdx.x * blockDim.x + threadIdx.x) >> 6);
  int gwaves = (int)((gridDim.x * blockDim.x) >> 6);
  float2 b1v = *(const float2*)&b1[lane * 2];
  float2 w2v = *(const float2*)&W2[lane * 2];
  float b2v = b2[0];
  for (int e = wave; e < n_edges; e += gwaves) {
    int s = src[e], d = dst[e];
    float2 gs = *(const float2*)&g[(size_t)s * 128 + lane * 2];
    float2 gd = *(const float2*)&g[(size_t)d * 128 + lane * 2];
    float t0 = fmaxf(gs.x - gd.x + b1v.x, 0.f);
    float t1 = fmaxf(gs.y - gd.y + b1v.y, 0.f);
    float acc = t0 * w2v.x + t1 * w2v.y;
    #pragma unroll
    for (int off = 1; off < 64; off <<= 1) acc += __shfl_xor(acc, off);
    if (lane == 0) {
      float a = fmaxf(acc + b2v, 0.f);
      a = 1.f / (1.f + __expf(-a));
      att[e] = a;
      atomicAdd(&denom[s], a);
    }
  }
}

__global__ __launch_bounds__(256) void k_hist(const int* __restrict__ dst,
                                              int* __restrict__ counts, int n_edges) {
  int i = blockIdx.x * blockDim.x + threadIdx.x;
  int stride = gridDim.x * blockDim.x;
  for (int e = i; e < n_edges; e += stride) atomicAdd(&counts[dst[e]], 1);
}

// One-block exclusive scan of counts[n] -> row_start[n+1]
__global__ __launch_bounds__(1024) void k_scan(const int* __restrict__ counts,
                                               int* __restrict__ row_start,
                                               int n, int total) {
  __shared__ int part[1024];
  int t = threadIdx.x;
  int per = (n + 1023) / 1024;
  int begin = t * per;
  int end = begin + per < n ? begin + per : n;
  int s = 0;
  for (int i = begin; i < end; ++i) s += counts[i];
  part[t] = s;
  __syncthreads();
  for (int off = 1; off < 1024; off <<= 1) {
    int v = (t >= off) ? part[t - off] : 0;
    __syncthreads();
    part[t] += v;
    __syncthreads();
  }
  int excl = (t == 0) ? 0 : part[t - 1];
  for (int i = begin; i < end; ++i) { row_start[i] = excl; excl += counts[i]; }
  if (t == 0) row_start[n] = total;
}

__global__ __launch_bounds__(256) void k_fill(const int* __restrict__ dst,
                                              const int* __restrict__ row_start,
                                              int* __restrict__ cursor,
                                              int* __restrict__ bucket, int n_edges) {
  int i = blockIdx.x * blockDim.x + threadIdx.x;
  int stride = gridDim.x * blockDim.x;
  for (int e = i; e < n_edges; e += stride) {
    int d = dst[e];
    int pos = atomicAdd(&cursor[d], 1);
    bucket[row_start[d] + pos] = e;
  }
}

__global__ __launch_bounds__(256) void k_agg(const float* __restrict__ h,
                                             const int* __restrict__ src,
                                             const int* __restrict__ att,      // float bits
                                             const float* __restrict__ attf,
                                             const float* __restrict__ denom,
                                             const int* __restrict__ row_start,
                                             const int* __restrict__ bucket,
                                             float* __restrict__ out, int n_nodes) {
  int lane = threadIdx.x & 63;
  int wave_in_blk = threadIdx.x >> 6;
  int d = blockIdx.x * 4 + wave_in_blk;
  if (d >= n_nodes) return;
  int beg = row_start[d], end = row_start[d + 1];
  float acc0 = 0.f, acc1 = 0.f;
  for (int i = beg; i < end; ++i) {
    int e = bucket[i];
    int s = src[e];
    float w = attf[e] / denom[s];
    float2 hv = *(const float2*)&h[(size_t)s * 128 + lane * 2];
    acc0 += w * hv.x;
    acc1 += w * hv.y;
  }
  out[(size_t)d * 128 + lane * 2] = acc0;
  out[(size_t)d * 128 + lane * 2 + 1] = acc1;
}

extern "C" void kernel_launch(void* const* d_in, const int* in_sizes, int n_in,
                              void* d_out, int out_size, void* d_ws, size_t ws_size,
                              hipStream_t stream) {
  const float* h   = (const float*)d_in[0];
  const int*   src = (const int*)d_in[1];
  const int*   dst = (const int*)d_in[2];
  const float* W1  = (const float*)d_in[3];
  const float* b1  = (const float*)d_in[4];
  const float* W2  = (const float*)d_in[5];
  const float* b2  = (const float*)d_in[6];
  float* out = (float*)d_out;

  int n_nodes = in_sizes[0] / 128;
  int n_edges = in_sizes[1];

  char* ws = (char*)d_ws;
  float* g         = (float*)ws;                                // n_nodes*128
  float* att       = g + (size_t)n_nodes * 128;                 // n_edges
  float* denom     = att + n_edges;                             // n_nodes
  int*   counts    = (int*)(denom + n_nodes);                   // n_nodes (reused as cursor)
  int*   row_start = counts + n_nodes;                          // n_nodes+1
  int*   bucket    = row_start + n_nodes + 1;                   // n_edges

  hipMemsetAsync(counts, 0, (size_t)n_nodes * sizeof(int), stream);
  hipMemsetAsync(denom, 0, (size_t)n_nodes * sizeof(float), stream);

  k_gemm<<<1024, 256, 0, stream>>>(h, W1, g, n_nodes);
  k_att<<<4096, 256, 0, stream>>>(g, src, dst, b1, W2, b2, att, denom, n_edges);
  k_hist<<<2048, 256, 0, stream>>>(dst, counts, n_edges);
  k_scan<<<1, 1024, 0, stream>>>(counts, row_start, n_nodes, n_edges);
  hipMemsetAsync(counts, 0, (size_t)n_nodes * sizeof(int), stream);  // reuse as cursor
  k_fill<<<2048, 256, 0, stream>>>(dst, row_start, counts, bucket, n_edges);
  k_agg<<<(50000 + 3) / 4 + 1, 256, 0, stream>>>(h, src, (const int*)att, att, denom,
                                                 row_start, bucket, out, n_nodes);
}

// Round 3
// 221.919 us; speedup vs baseline: 3.0461x; 1.8735x over previous
//
#include <hip/hip_runtime.h>

// Pipeline (all fp16-packed gathers, fp32 math):
//   k_gemm : g = h@W1 (fp16x2 out), also emits hh = fp16x2 copy of h
//   k_att  : att[e] = sigmoid(relu(relu(g[s]-g[d]+b1).W2+b2)); denom[s]+=att; counts[d]+=1
//   scanA/B/C : 256-block exclusive scan of counts -> row_start; zeroes counts (cursor)
//   k_fill : bucket[row_start[d]+pos] = (src, w=att/denom[src])   (int2)
//   k_agg  : out[d] = sum over bucket[d] of w * hh[src]           (pull, no atomics)

typedef unsigned int uint;

static __device__ __forceinline__ uint pack_f16(float a, float b) {
  _Float16 ha = (_Float16)a, hb = (_Float16)b;
  unsigned short ua = __builtin_bit_cast(unsigned short, ha);
  unsigned short ub = __builtin_bit_cast(unsigned short, hb);
  return ((uint)ub << 16) | ua;
}
static __device__ __forceinline__ float2 unpack_f16(uint u) {
  _Float16 lo = __builtin_bit_cast(_Float16, (unsigned short)(u & 0xffffu));
  _Float16 hi = __builtin_bit_cast(_Float16, (unsigned short)(u >> 16));
  return make_float2((float)lo, (float)hi);
}

__global__ __launch_bounds__(256) void k_gemm(const float* __restrict__ h,
                                              const float* __restrict__ W1,
                                              uint* __restrict__ gh,
                                              uint* __restrict__ hh,
                                              int n_nodes) {
  __shared__ float w1s[128 * 128];
  __shared__ float rowbuf[4][4][128];
  int tid = threadIdx.x;
  for (int i = tid * 4; i < 128 * 128; i += 256 * 4)
    *(float4*)&w1s[i] = *(const float4*)&W1[i];
  int wave = tid >> 6, lane = tid & 63;
  int n0 = (blockIdx.x * 4 + wave) * 4;
  #pragma unroll
  for (int u = 0; u < 4; ++u) {
    int n = n0 + u;
    float2 hv = make_float2(0.f, 0.f);
    if (n < n_nodes) {
      hv = *(const float2*)&h[(size_t)n * 128 + lane * 2];
      hh[(size_t)n * 64 + lane] = pack_f16(hv.x, hv.y);
    }
    rowbuf[wave][u][lane * 2] = hv.x;
    rowbuf[wave][u][lane * 2 + 1] = hv.y;
  }
  __syncthreads();
  float a0[4] = {0.f, 0.f, 0.f, 0.f}, a1[4] = {0.f, 0.f, 0.f, 0.f};
  #pragma unroll 4
  for (int k = 0; k < 128; k += 4) {
    float2 wv[4];
    #pragma unroll
    for (int kk = 0; kk < 4; ++kk)
      wv[kk] = *(float2*)&w1s[(k + kk) * 128 + lane * 2];  // cols 2lane,2lane+1
    #pragma unroll
    for (int u = 0; u < 4; ++u) {
      float4 hk = *(float4*)&rowbuf[wave][u][k];
      a0[u] = fmaf(hk.x, wv[0].x, a0[u]); a1[u] = fmaf(hk.x, wv[0].y, a1[u]);
      a0[u] = fmaf(hk.y, wv[1].x, a0[u]); a1[u] = fmaf(hk.y, wv[1].y, a1[u]);
      a0[u] = fmaf(hk.z, wv[2].x, a0[u]); a1[u] = fmaf(hk.z, wv[2].y, a1[u]);
      a0[u] = fmaf(hk.w, wv[3].x, a0[u]); a1[u] = fmaf(hk.w, wv[3].y, a1[u]);
    }
  }
  #pragma unroll
  for (int u = 0; u < 4; ++u) {
    int n = n0 + u;
    if (n < n_nodes) gh[(size_t)n * 64 + lane] = pack_f16(a0[u], a1[u]);
  }
}

__global__ __launch_bounds__(256) void k_att(const uint* __restrict__ gh,
                                             const int* __restrict__ src,
                                             const int* __restrict__ dst,
                                             const float* __restrict__ b1,
                                             const float* __restrict__ W2,
                                             const float* __restrict__ b2,
                                             float* __restrict__ att,
                                             float* __restrict__ denom,
                                             int* __restrict__ counts,
                                             int n_edges) {
  int lane = threadIdx.x & 63;
  int wid = (int)((blockIdx.x * blockDim.x + threadIdx.x) >> 6);
  int gw = (int)((gridDim.x * blockDim.x) >> 6);
  float2 b1v = *(const float2*)&b1[lane * 2];
  float2 w2v = *(const float2*)&W2[lane * 2];
  float b2v = b2[0];
  for (int e = wid; e < n_edges; e += gw) {
    int s = src[e], d = dst[e];
    float2 gs = unpack_f16(gh[(size_t)s * 64 + lane]);
    float2 gd = unpack_f16(gh[(size_t)d * 64 + lane]);
    float t0 = fmaxf(gs.x - gd.x + b1v.x, 0.f);
    float t1 = fmaxf(gs.y - gd.y + b1v.y, 0.f);
    float acc = fmaf(t0, w2v.x, t1 * w2v.y);
    #pragma unroll
    for (int off = 1; off < 64; off <<= 1) acc += __shfl_xor(acc, off);
    if (lane == 0) {
      float a = fmaxf(acc + b2v, 0.f);
      a = 1.f / (1.f + __expf(-a));
      att[e] = a;
      atomicAdd(&denom[s], a);
      atomicAdd(&counts[d], 1);
    }
  }
}

__global__ __launch_bounds__(256) void k_scanA(const int* __restrict__ counts,
                                               int* __restrict__ partials,
                                               int n, int chunk) {
  __shared__ int red[256];
  int b = blockIdx.x, t = threadIdx.x;
  int idx = b * chunk + t;
  red[t] = (t < chunk && idx < n) ? counts[idx] : 0;
  __syncthreads();
  for (int off = 128; off > 0; off >>= 1) {
    if (t < off) red[t] += red[t + off];
    __syncthreads();
  }
  if (t == 0) partials[b] = red[0];
}

__global__ __launch_bounds__(256) void k_scanB(int* __restrict__ partials,
                                               int* __restrict__ row_start,
                                               int n, int total) {
  __shared__ int p[256];
  int t = threadIdx.x;
  int orig = partials[t];
  p[t] = orig;
  __syncthreads();
  #pragma unroll
  for (int off = 1; off < 256; off <<= 1) {
    int v = (t >= off) ? p[t - off] : 0;
    __syncthreads();
    p[t] += v;
    __syncthreads();
  }
  partials[t] = p[t] - orig;  // exclusive base per block
  if (t == 0) row_start[n] = total;
}

__global__ __launch_bounds__(256) void k_scanC(int* __restrict__ counts,
                                               const int* __restrict__ partials,
                                               int* __restrict__ row_start,
                                               int n, int chunk) {
  __shared__ int p[256];
  int b = blockIdx.x, t = threadIdx.x;
  int idx = b * chunk + t;
  bool ok = (t < chunk && idx < n);
  int orig = ok ? counts[idx] : 0;
  p[t] = orig;
  __syncthreads();
  #pragma unroll
  for (int off = 1; off < 256; off <<= 1) {
    int v = (t >= off) ? p[t - off] : 0;
    __syncthreads();
    p[t] += v;
    __syncthreads();
  }
  if (ok) {
    row_start[idx] = partials[b] + p[t] - orig;
    counts[idx] = 0;  // becomes cursor for k_fill
  }
}

__global__ __launch_bounds__(256) void k_fill(const int* __restrict__ src,
                                              const int* __restrict__ dst,
                                              const float* __restrict__ att,
                                              const float* __restrict__ denom,
                                              const int* __restrict__ row_start,
                                              int* __restrict__ cursor,
                                              int2* __restrict__ bucket,
                                              int n_edges) {
  int i = blockIdx.x * blockDim.x + threadIdx.x;
  int stride = gridDim.x * blockDim.x;
  for (int e = i; e < n_edges; e += stride) {
    int d = dst[e], s = src[e];
    float w = att[e] / denom[s];
    int pos = atomicAdd(&cursor[d], 1);
    bucket[row_start[d] + pos] = make_int2(s, __float_as_int(w));
  }
}

__global__ __launch_bounds__(256) void k_agg(const uint* __restrict__ hh,
                                             const int* __restrict__ row_start,
                                             const int2* __restrict__ bucket,
                                             float* __restrict__ out, int n_nodes) {
  int lane = threadIdx.x & 63;
  int d = blockIdx.x * 4 + (threadIdx.x >> 6);
  if (d >= n_nodes) return;
  int beg = row_start[d], end = row_start[d + 1];
  float acc0 = 0.f, acc1 = 0.f;
  for (int base = beg; base < end; base += 64) {
    int cnt = end - base;
    if (cnt > 64) cnt = 64;
    int2 ew = make_int2(0, 0);
    if (lane < cnt) ew = bucket[base + lane];
    int j = 0;
    for (; j + 4 <= cnt; j += 4) {
      int s0 = __shfl(ew.x, j),     s1 = __shfl(ew.x, j + 1);
      int s2 = __shfl(ew.x, j + 2), s3 = __shfl(ew.x, j + 3);
      float w0 = __int_as_float(__shfl(ew.y, j));
      float w1 = __int_as_float(__shfl(ew.y, j + 1));
      float w2 = __int_as_float(__shfl(ew.y, j + 2));
      float w3 = __int_as_float(__shfl(ew.y, j + 3));
      uint v0 = hh[(size_t)s0 * 64 + lane];
      uint v1 = hh[(size_t)s1 * 64 + lane];
      uint v2 = hh[(size_t)s2 * 64 + lane];
      uint v3 = hh[(size_t)s3 * 64 + lane];
      float2 f0 = unpack_f16(v0), f1 = unpack_f16(v1);
      float2 f2 = unpack_f16(v2), f3 = unpack_f16(v3);
      acc0 = fmaf(w0, f0.x, acc0); acc1 = fmaf(w0, f0.y, acc1);
      acc0 = fmaf(w1, f1.x, acc0); acc1 = fmaf(w1, f1.y, acc1);
      acc0 = fmaf(w2, f2.x, acc0); acc1 = fmaf(w2, f2.y, acc1);
      acc0 = fmaf(w3, f3.x, acc0); acc1 = fmaf(w3, f3.y, acc1);
    }
    for (; j < cnt; ++j) {
      int s = __shfl(ew.x, j);
      float w = __int_as_float(__shfl(ew.y, j));
      float2 f = unpack_f16(hh[(size_t)s * 64 + lane]);
      acc0 = fmaf(w, f.x, acc0); acc1 = fmaf(w, f.y, acc1);
    }
  }
  *(float2*)&out[(size_t)d * 128 + lane * 2] = make_float2(acc0, acc1);
}

extern "C" void kernel_launch(void* const* d_in, const int* in_sizes, int n_in,
                              void* d_out, int out_size, void* d_ws, size_t ws_size,
                              hipStream_t stream) {
  const float* h   = (const float*)d_in[0];
  const int*   src = (const int*)d_in[1];
  const int*   dst = (const int*)d_in[2];
  const float* W1  = (const float*)d_in[3];
  const float* b1  = (const float*)d_in[4];
  const float* W2  = (const float*)d_in[5];
  const float* b2  = (const float*)d_in[6];
  float* out = (float*)d_out;

  int n_nodes = in_sizes[0] / 128;
  int n_edges = in_sizes[1];

  char* ws = (char*)d_ws;
  uint*  gh        = (uint*)ws;                        // n*64
  uint*  hh        = gh + (size_t)n_nodes * 64;        // n*64
  float* att       = (float*)(hh + (size_t)n_nodes * 64);  // E
  float* denom     = att + n_edges;                    // n
  int*   counts    = (int*)(denom + n_nodes);          // n (cursor later)
  int*   row_start = counts + n_nodes;                 // n+1
  int*   partials  = row_start + n_nodes + 1;          // 256
  int2*  bucket    = (int2*)(((uintptr_t)(partials + 256) + 7) & ~(uintptr_t)7);

  // zero denom + counts in one shot (adjacent)
  hipMemsetAsync(denom, 0, (size_t)2 * n_nodes * sizeof(float), stream);

  int chunk = (n_nodes + 255) / 256;
  k_gemm <<<(n_nodes + 15) / 16, 256, 0, stream>>>(h, W1, gh, hh, n_nodes);
  k_att  <<<2048, 256, 0, stream>>>(gh, src, dst, b1, W2, b2, att, denom, counts, n_edges);
  k_scanA<<<256, 256, 0, stream>>>(counts, partials, n_nodes, chunk);
  k_scanB<<<1, 256, 0, stream>>>(partials, row_start, n_nodes, n_edges);
  k_scanC<<<256, 256, 0, stream>>>(counts, partials, row_start, n_nodes, chunk);
  k_fill <<<2048, 256, 0, stream>>>(src, dst, att, denom, row_start, counts, bucket, n_edges);
  k_agg  <<<(n_nodes + 3) / 4, 256, 0, stream>>>(hh, row_start, bucket, out, n_nodes);
}

// Round 4
// 197.701 us; speedup vs baseline: 3.4192x; 1.1225x over previous
//
#include <hip/hip_runtime.h>

// Pipeline (fp16-packed gathers, fp32 math):
//   k_gemm : g = h@W1 (fp16x2 out), also emits hh = fp16x2 copy of h
//   k_att  : 16 lanes/edge, uint4 row loads; att=sigmoid(relu(relu(gs-gd+b1).W2+b2));
//            denom[s]+=att; counts[d]+=1
//   scanA/B/C : 256-block exclusive scan of counts -> row_start; zeroes counts
//   k_fill : bucket[row_start[d]+pos] = (src, w=att/denom[src])   (int2)
//   k_agg  : wave/dst, 4 sub-groups x 16 lanes, uint4 loads; out[d]=sum w*hh[src]

typedef unsigned int uint;

static __device__ __forceinline__ uint pack_f16(float a, float b) {
  _Float16 ha = (_Float16)a, hb = (_Float16)b;
  unsigned short ua = __builtin_bit_cast(unsigned short, ha);
  unsigned short ub = __builtin_bit_cast(unsigned short, hb);
  return ((uint)ub << 16) | ua;
}
static __device__ __forceinline__ float2 unpack_f16(uint u) {
  _Float16 lo = __builtin_bit_cast(_Float16, (unsigned short)(u & 0xffffu));
  _Float16 hi = __builtin_bit_cast(_Float16, (unsigned short)(u >> 16));
  return make_float2((float)lo, (float)hi);
}

__global__ __launch_bounds__(256) void k_gemm(const float* __restrict__ h,
                                              const float* __restrict__ W1,
                                              uint* __restrict__ gh,
                                              uint* __restrict__ hh,
                                              int n_nodes) {
  __shared__ float w1s[128 * 128];
  __shared__ float rowbuf[4][4][128];
  int tid = threadIdx.x;
  for (int i = tid * 4; i < 128 * 128; i += 256 * 4)
    *(float4*)&w1s[i] = *(const float4*)&W1[i];
  int wave = tid >> 6, lane = tid & 63;
  int n0 = (blockIdx.x * 4 + wave) * 4;
  #pragma unroll
  for (int u = 0; u < 4; ++u) {
    int n = n0 + u;
    float2 hv = make_float2(0.f, 0.f);
    if (n < n_nodes) {
      hv = *(const float2*)&h[(size_t)n * 128 + lane * 2];
      hh[(size_t)n * 64 + lane] = pack_f16(hv.x, hv.y);
    }
    rowbuf[wave][u][lane * 2] = hv.x;
    rowbuf[wave][u][lane * 2 + 1] = hv.y;
  }
  __syncthreads();
  float a0[4] = {0.f, 0.f, 0.f, 0.f}, a1[4] = {0.f, 0.f, 0.f, 0.f};
  #pragma unroll 4
  for (int k = 0; k < 128; k += 4) {
    float2 wv[4];
    #pragma unroll
    for (int kk = 0; kk < 4; ++kk)
      wv[kk] = *(float2*)&w1s[(k + kk) * 128 + lane * 2];
    #pragma unroll
    for (int u = 0; u < 4; ++u) {
      float4 hk = *(float4*)&rowbuf[wave][u][k];
      a0[u] = fmaf(hk.x, wv[0].x, a0[u]); a1[u] = fmaf(hk.x, wv[0].y, a1[u]);
      a0[u] = fmaf(hk.y, wv[1].x, a0[u]); a1[u] = fmaf(hk.y, wv[1].y, a1[u]);
      a0[u] = fmaf(hk.z, wv[2].x, a0[u]); a1[u] = fmaf(hk.z, wv[2].y, a1[u]);
      a0[u] = fmaf(hk.w, wv[3].x, a0[u]); a1[u] = fmaf(hk.w, wv[3].y, a1[u]);
    }
  }
  #pragma unroll
  for (int u = 0; u < 4; ++u) {
    int n = n0 + u;
    if (n < n_nodes) gh[(size_t)n * 64 + lane] = pack_f16(a0[u], a1[u]);
  }
}

__global__ __launch_bounds__(256) void k_att(const uint4* __restrict__ gh4,
                                             const int* __restrict__ src,
                                             const int* __restrict__ dst,
                                             const float* __restrict__ b1,
                                             const float* __restrict__ W2,
                                             const float* __restrict__ b2,
                                             float* __restrict__ att,
                                             float* __restrict__ denom,
                                             int* __restrict__ counts,
                                             int n_edges) {
  int lane = threadIdx.x & 63;
  int sub = lane >> 4, l16 = lane & 15;
  int wid = (int)((blockIdx.x * blockDim.x + threadIdx.x) >> 6);
  int gw = (int)((gridDim.x * blockDim.x) >> 6);
  // per-lane constants: features l16*8 .. l16*8+7
  float4 b1a = *(const float4*)&b1[l16 * 8];
  float4 b1b = *(const float4*)&b1[l16 * 8 + 4];
  float4 w2a = *(const float4*)&W2[l16 * 8];
  float4 w2b = *(const float4*)&W2[l16 * 8 + 4];
  float b2v = b2[0];
  for (int e0 = wid * 4; e0 < n_edges; e0 += gw * 4) {
    int e = e0 + sub;
    bool valid = e < n_edges;
    int s = 0, d = 0;
    float acc = 0.f;
    if (valid) {
      s = src[e];
      d = dst[e];
      uint4 us = gh4[(size_t)s * 16 + l16];
      uint4 ud = gh4[(size_t)d * 16 + l16];
      float2 s0 = unpack_f16(us.x), s1 = unpack_f16(us.y);
      float2 s2 = unpack_f16(us.z), s3 = unpack_f16(us.w);
      float2 d0 = unpack_f16(ud.x), d1 = unpack_f16(ud.y);
      float2 d2 = unpack_f16(ud.z), d3 = unpack_f16(ud.w);
      float t;
      t = fmaxf(s0.x - d0.x + b1a.x, 0.f); acc = fmaf(t, w2a.x, acc);
      t = fmaxf(s0.y - d0.y + b1a.y, 0.f); acc = fmaf(t, w2a.y, acc);
      t = fmaxf(s1.x - d1.x + b1a.z, 0.f); acc = fmaf(t, w2a.z, acc);
      t = fmaxf(s1.y - d1.y + b1a.w, 0.f); acc = fmaf(t, w2a.w, acc);
      t = fmaxf(s2.x - d2.x + b1b.x, 0.f); acc = fmaf(t, w2b.x, acc);
      t = fmaxf(s2.y - d2.y + b1b.y, 0.f); acc = fmaf(t, w2b.y, acc);
      t = fmaxf(s3.x - d3.x + b1b.z, 0.f); acc = fmaf(t, w2b.z, acc);
      t = fmaxf(s3.y - d3.y + b1b.w, 0.f); acc = fmaf(t, w2b.w, acc);
    }
    acc += __shfl_xor(acc, 1);
    acc += __shfl_xor(acc, 2);
    acc += __shfl_xor(acc, 4);
    acc += __shfl_xor(acc, 8);
    if (l16 == 0 && valid) {
      float a = fmaxf(acc + b2v, 0.f);
      a = 1.f / (1.f + __expf(-a));
      att[e] = a;
      atomicAdd(&denom[s], a);
      atomicAdd(&counts[d], 1);
    }
  }
}

__global__ __launch_bounds__(256) void k_scanA(const int* __restrict__ counts,
                                               int* __restrict__ partials,
                                               int n, int chunk) {
  __shared__ int red[256];
  int b = blockIdx.x, t = threadIdx.x;
  int idx = b * chunk + t;
  red[t] = (t < chunk && idx < n) ? counts[idx] : 0;
  __syncthreads();
  for (int off = 128; off > 0; off >>= 1) {
    if (t < off) red[t] += red[t + off];
    __syncthreads();
  }
  if (t == 0) partials[b] = red[0];
}

__global__ __launch_bounds__(256) void k_scanB(int* __restrict__ partials,
                                               int* __restrict__ row_start,
                                               int n, int total) {
  __shared__ int p[256];
  int t = threadIdx.x;
  int orig = partials[t];
  p[t] = orig;
  __syncthreads();
  #pragma unroll
  for (int off = 1; off < 256; off <<= 1) {
    int v = (t >= off) ? p[t - off] : 0;
    __syncthreads();
    p[t] += v;
    __syncthreads();
  }
  partials[t] = p[t] - orig;
  if (t == 0) row_start[n] = total;
}

__global__ __launch_bounds__(256) void k_scanC(int* __restrict__ counts,
                                               const int* __restrict__ partials,
                                               int* __restrict__ row_start,
                                               int n, int chunk) {
  __shared__ int p[256];
  int b = blockIdx.x, t = threadIdx.x;
  int idx = b * chunk + t;
  bool ok = (t < chunk && idx < n);
  int orig = ok ? counts[idx] : 0;
  p[t] = orig;
  __syncthreads();
  #pragma unroll
  for (int off = 1; off < 256; off <<= 1) {
    int v = (t >= off) ? p[t - off] : 0;
    __syncthreads();
    p[t] += v;
    __syncthreads();
  }
  if (ok) {
    row_start[idx] = partials[b] + p[t] - orig;
    counts[idx] = 0;  // becomes cursor for k_fill
  }
}

__global__ __launch_bounds__(256) void k_fill(const int* __restrict__ src,
                                              const int* __restrict__ dst,
                                              const float* __restrict__ att,
                                              const float* __restrict__ denom,
                                              const int* __restrict__ row_start,
                                              int* __restrict__ cursor,
                                              int2* __restrict__ bucket,
                                              int n_edges) {
  int i = blockIdx.x * blockDim.x + threadIdx.x;
  int stride = gridDim.x * blockDim.x;
  for (int e = i; e < n_edges; e += stride) {
    int d = dst[e], s = src[e];
    float w = att[e] / denom[s];
    int pos = atomicAdd(&cursor[d], 1);
    bucket[row_start[d] + pos] = make_int2(s, __float_as_int(w));
  }
}

__global__ __launch_bounds__(256) void k_agg(const uint4* __restrict__ hh4,
                                             const int* __restrict__ row_start,
                                             const int2* __restrict__ bucket,
                                             float* __restrict__ out, int n_nodes) {
  int lane = threadIdx.x & 63;
  int sub = lane >> 4, l16 = lane & 15;
  int d = blockIdx.x * 4 + (threadIdx.x >> 6);
  if (d >= n_nodes) return;
  int beg = row_start[d], end = row_start[d + 1];
  int cnt = end - beg;
  float a0 = 0.f, a1 = 0.f, a2 = 0.f, a3 = 0.f;
  float a4 = 0.f, a5 = 0.f, a6 = 0.f, a7 = 0.f;
  for (int base = 0; base < cnt; base += 64) {
    int nb = cnt - base; if (nb > 64) nb = 64;
    int2 ew = make_int2(0, 0);
    if (lane < nb) ew = bucket[beg + base + lane];
    int steps = (nb + 3) >> 2;
    for (int j = 0; j < steps; ++j) {
      int idx = j * 4 + sub;          // this sub-group's edge this step
      int s = __shfl(ew.x, idx);
      float w = __int_as_float(__shfl(ew.y, idx));
      if (idx < nb) {
        uint4 v = hh4[(size_t)s * 16 + l16];
        float2 f0 = unpack_f16(v.x), f1 = unpack_f16(v.y);
        float2 f2 = unpack_f16(v.z), f3 = unpack_f16(v.w);
        a0 = fmaf(w, f0.x, a0); a1 = fmaf(w, f0.y, a1);
        a2 = fmaf(w, f1.x, a2); a3 = fmaf(w, f1.y, a3);
        a4 = fmaf(w, f2.x, a4); a5 = fmaf(w, f2.y, a5);
        a6 = fmaf(w, f3.x, a6); a7 = fmaf(w, f3.y, a7);
      }
    }
  }
  #pragma unroll
  for (int off = 16; off < 64; off <<= 1) {
    a0 += __shfl_xor(a0, off); a1 += __shfl_xor(a1, off);
    a2 += __shfl_xor(a2, off); a3 += __shfl_xor(a3, off);
    a4 += __shfl_xor(a4, off); a5 += __shfl_xor(a5, off);
    a6 += __shfl_xor(a6, off); a7 += __shfl_xor(a7, off);
  }
  if (sub == 0) {
    *(float4*)&out[(size_t)d * 128 + l16 * 8]     = make_float4(a0, a1, a2, a3);
    *(float4*)&out[(size_t)d * 128 + l16 * 8 + 4] = make_float4(a4, a5, a6, a7);
  }
}

extern "C" void kernel_launch(void* const* d_in, const int* in_sizes, int n_in,
                              void* d_out, int out_size, void* d_ws, size_t ws_size,
                              hipStream_t stream) {
  const float* h   = (const float*)d_in[0];
  const int*   src = (const int*)d_in[1];
  const int*   dst = (const int*)d_in[2];
  const float* W1  = (const float*)d_in[3];
  const float* b1  = (const float*)d_in[4];
  const float* W2  = (const float*)d_in[5];
  const float* b2  = (const float*)d_in[6];
  float* out = (float*)d_out;

  int n_nodes = in_sizes[0] / 128;
  int n_edges = in_sizes[1];

  char* ws = (char*)d_ws;
  uint*  gh        = (uint*)ws;                            // n*64
  uint*  hh        = gh + (size_t)n_nodes * 64;            // n*64
  float* att       = (float*)(hh + (size_t)n_nodes * 64);  // E
  float* denom     = att + n_edges;                        // n
  int*   counts    = (int*)(denom + n_nodes);              // n (cursor later)
  int*   row_start = counts + n_nodes;                     // n+1
  int*   partials  = row_start + n_nodes + 1;              // 256
  int2*  bucket    = (int2*)(((uintptr_t)(partials + 256) + 15) & ~(uintptr_t)15);

  hipMemsetAsync(denom, 0, (size_t)2 * n_nodes * sizeof(float), stream);

  int chunk = (n_nodes + 255) / 256;
  k_gemm <<<(n_nodes + 15) / 16, 256, 0, stream>>>(h, W1, gh, hh, n_nodes);
  k_att  <<<2048, 256, 0, stream>>>((const uint4*)gh, src, dst, b1, W2, b2,
                                    att, denom, counts, n_edges);
  k_scanA<<<256, 256, 0, stream>>>(counts, partials, n_nodes, chunk);
  k_scanB<<<1, 256, 0, stream>>>(partials, row_start, n_nodes, n_edges);
  k_scanC<<<256, 256, 0, stream>>>(counts, partials, row_start, n_nodes, chunk);
  k_fill <<<2048, 256, 0, stream>>>(src, dst, att, denom, row_start, counts, bucket, n_edges);
  k_agg  <<<(n_nodes + 3) / 4, 256, 0, stream>>>((const uint4*)hh, row_start, bucket, out, n_nodes);
}

// Round 5
// 152.121 us; speedup vs baseline: 4.4437x; 1.2996x over previous
//
#include <hip/hip_runtime.h>

// Pipeline (fp16-packed gathers, fp32 math, MFMA node-GEMM):
//   k_transpose : W1 fp32 -> W1^T bf16, pre-swizzled byte image (T2 st-pattern)
//   k_gemm : g = h@W1 via mfma_f32_16x16x32_bf16; emits hh = fp16x2 copy of h
//   k_att  : 16 lanes/edge, uint4 row loads; att=sigmoid(relu(relu(gs-gd+b1).W2+b2))
//   scanA/B/C : 256-block exclusive scan of counts -> row_start
//   k_fill : bucket[row_start[d]+pos] = (src, w=att/denom[src])
//   k_agg  : wave/dst, 4 sub-groups x 16 lanes, uint4 loads; out[d]=sum w*hh[src]

typedef unsigned int uint;
typedef unsigned short ushort;
typedef __attribute__((ext_vector_type(8))) short short8;
typedef __attribute__((ext_vector_type(4))) float f32x4;

static __device__ __forceinline__ uint pack_f16(float a, float b) {
  _Float16 ha = (_Float16)a, hb = (_Float16)b;
  unsigned short ua = __builtin_bit_cast(unsigned short, ha);
  unsigned short ub = __builtin_bit_cast(unsigned short, hb);
  return ((uint)ub << 16) | ua;
}
static __device__ __forceinline__ float2 unpack_f16(uint u) {
  _Float16 lo = __builtin_bit_cast(_Float16, (unsigned short)(u & 0xffffu));
  _Float16 hi = __builtin_bit_cast(_Float16, (unsigned short)(u >> 16));
  return make_float2((float)lo, (float)hi);
}
static __device__ __forceinline__ ushort f2bf(float x) {
  uint u = __float_as_uint(x);
  u += 0x7fffu + ((u >> 16) & 1u);   // RNE
  return (ushort)(u >> 16);
}

// W1[k][n] fp32 -> w1t_swz: W1^T[n][k] bf16 at byte n*256 + ((k*2) ^ ((n&7)<<4))
__global__ __launch_bounds__(256) void k_transpose(const float* __restrict__ W1,
                                                   ushort* __restrict__ w1t_swz) {
  int idx = blockIdx.x * 256 + threadIdx.x;   // 64 blocks -> 16384
  int n = idx >> 7, k = idx & 127;
  float v = W1[k * 128 + n];
  int byte_off = n * 256 + ((k * 2) ^ ((n & 7) << 4));
  w1t_swz[byte_off >> 1] = f2bf(v);
}

__global__ __launch_bounds__(256) void k_gemm(const float* __restrict__ h,
                                              const ushort* __restrict__ w1t_swz,
                                              uint* __restrict__ gh,
                                              uint4* __restrict__ hh4,
                                              int n_nodes) {
  __shared__ ushort w1s[16384];   // 32 KiB swizzled W1^T image
  int tid = threadIdx.x;
  {
    const uint4* srcw = (const uint4*)w1t_swz;
    uint4* dstw = (uint4*)w1s;
    #pragma unroll
    for (int i = 0; i < 8; ++i) dstw[tid + 256 * i] = srcw[tid + 256 * i];
  }
  __syncthreads();
  int wave = tid >> 6, lane = tid & 63;
  int tile = blockIdx.x * 4 + wave;
  if (tile * 16 >= n_nodes) return;           // tiles are exact (50000 = 3125*16)
  int n0 = tile * 16;
  int l15 = lane & 15, kq = lane >> 4;        // kq in 0..3
  int row = n0 + l15;

  f32x4 acc[8];
  #pragma unroll
  for (int ct = 0; ct < 8; ++ct) acc[ct] = (f32x4){0.f, 0.f, 0.f, 0.f};

  #pragma unroll
  for (int kb = 0; kb < 4; ++kb) {
    const float* hp = &h[(size_t)row * 128 + kb * 32 + kq * 8];
    float4 p0 = *(const float4*)hp;
    float4 p1 = *(const float4*)(hp + 4);
    short8 a;
    a[0] = (short)f2bf(p0.x); a[1] = (short)f2bf(p0.y);
    a[2] = (short)f2bf(p0.z); a[3] = (short)f2bf(p0.w);
    a[4] = (short)f2bf(p1.x); a[5] = (short)f2bf(p1.y);
    a[6] = (short)f2bf(p1.z); a[7] = (short)f2bf(p1.w);
    uint4 hv;
    hv.x = pack_f16(p0.x, p0.y); hv.y = pack_f16(p0.z, p0.w);
    hv.z = pack_f16(p1.x, p1.y); hv.w = pack_f16(p1.z, p1.w);
    hh4[(size_t)row * 16 + kb * 4 + kq] = hv;
    #pragma unroll
    for (int ct = 0; ct < 8; ++ct) {
      int n = ct * 16 + l15;
      int byte_off = n * 256 + (((kb * 64) + kq * 16) ^ ((n & 7) << 4));
      short8 b = *(const short8*)((const char*)w1s + byte_off);
      acc[ct] = __builtin_amdgcn_mfma_f32_16x16x32_bf16(a, b, acc[ct], 0, 0, 0);
    }
  }
  // C/D: col = lane&15, row = (lane>>4)*4 + reg
  ushort* gh16 = (ushort*)gh;
  #pragma unroll
  for (int ct = 0; ct < 8; ++ct) {
    #pragma unroll
    for (int r = 0; r < 4; ++r) {
      int orow = n0 + kq * 4 + r;
      _Float16 v = (_Float16)acc[ct][r];
      gh16[(size_t)orow * 128 + ct * 16 + l15] = __builtin_bit_cast(unsigned short, v);
    }
  }
}

__global__ __launch_bounds__(256) void k_att(const uint4* __restrict__ gh4,
                                             const int* __restrict__ src,
                                             const int* __restrict__ dst,
                                             const float* __restrict__ b1,
                                             const float* __restrict__ W2,
                                             const float* __restrict__ b2,
                                             float* __restrict__ att,
                                             float* __restrict__ denom,
                                             int* __restrict__ counts,
                                             int n_edges) {
  int lane = threadIdx.x & 63;
  int sub = lane >> 4, l16 = lane & 15;
  int wid = (int)((blockIdx.x * blockDim.x + threadIdx.x) >> 6);
  int gw = (int)((gridDim.x * blockDim.x) >> 6);
  float4 b1a = *(const float4*)&b1[l16 * 8];
  float4 b1b = *(const float4*)&b1[l16 * 8 + 4];
  float4 w2a = *(const float4*)&W2[l16 * 8];
  float4 w2b = *(const float4*)&W2[l16 * 8 + 4];
  float b2v = b2[0];
  for (int e0 = wid * 4; e0 < n_edges; e0 += gw * 4) {
    int e = e0 + sub;
    bool valid = e < n_edges;
    int s = 0, d = 0;
    float acc = 0.f;
    if (valid) {
      s = src[e];
      d = dst[e];
      uint4 us = gh4[(size_t)s * 16 + l16];
      uint4 ud = gh4[(size_t)d * 16 + l16];
      float2 s0 = unpack_f16(us.x), s1 = unpack_f16(us.y);
      float2 s2 = unpack_f16(us.z), s3 = unpack_f16(us.w);
      float2 d0 = unpack_f16(ud.x), d1 = unpack_f16(ud.y);
      float2 d2 = unpack_f16(ud.z), d3 = unpack_f16(ud.w);
      float t;
      t = fmaxf(s0.x - d0.x + b1a.x, 0.f); acc = fmaf(t, w2a.x, acc);
      t = fmaxf(s0.y - d0.y + b1a.y, 0.f); acc = fmaf(t, w2a.y, acc);
      t = fmaxf(s1.x - d1.x + b1a.z, 0.f); acc = fmaf(t, w2a.z, acc);
      t = fmaxf(s1.y - d1.y + b1a.w, 0.f); acc = fmaf(t, w2a.w, acc);
      t = fmaxf(s2.x - d2.x + b1b.x, 0.f); acc = fmaf(t, w2b.x, acc);
      t = fmaxf(s2.y - d2.y + b1b.y, 0.f); acc = fmaf(t, w2b.y, acc);
      t = fmaxf(s3.x - d3.x + b1b.z, 0.f); acc = fmaf(t, w2b.z, acc);
      t = fmaxf(s3.y - d3.y + b1b.w, 0.f); acc = fmaf(t, w2b.w, acc);
    }
    acc += __shfl_xor(acc, 1);
    acc += __shfl_xor(acc, 2);
    acc += __shfl_xor(acc, 4);
    acc += __shfl_xor(acc, 8);
    if (l16 == 0 && valid) {
      float a = fmaxf(acc + b2v, 0.f);
      a = 1.f / (1.f + __expf(-a));
      att[e] = a;
      atomicAdd(&denom[s], a);
      atomicAdd(&counts[d], 1);
    }
  }
}

__global__ __launch_bounds__(256) void k_scanA(const int* __restrict__ counts,
                                               int* __restrict__ partials,
                                               int n, int chunk) {
  __shared__ int red[256];
  int b = blockIdx.x, t = threadIdx.x;
  int idx = b * chunk + t;
  red[t] = (t < chunk && idx < n) ? counts[idx] : 0;
  __syncthreads();
  for (int off = 128; off > 0; off >>= 1) {
    if (t < off) red[t] += red[t + off];
    __syncthreads();
  }
  if (t == 0) partials[b] = red[0];
}

__global__ __launch_bounds__(256) void k_scanB(int* __restrict__ partials,
                                               int* __restrict__ row_start,
                                               int n, int total) {
  __shared__ int p[256];
  int t = threadIdx.x;
  int orig = partials[t];
  p[t] = orig;
  __syncthreads();
  #pragma unroll
  for (int off = 1; off < 256; off <<= 1) {
    int v = (t >= off) ? p[t - off] : 0;
    __syncthreads();
    p[t] += v;
    __syncthreads();
  }
  partials[t] = p[t] - orig;
  if (t == 0) row_start[n] = total;
}

__global__ __launch_bounds__(256) void k_scanC(int* __restrict__ counts,
                                               const int* __restrict__ partials,
                                               int* __restrict__ row_start,
                                               int n, int chunk) {
  __shared__ int p[256];
  int b = blockIdx.x, t = threadIdx.x;
  int idx = b * chunk + t;
  bool ok = (t < chunk && idx < n);
  int orig = ok ? counts[idx] : 0;
  p[t] = orig;
  __syncthreads();
  #pragma unroll
  for (int off = 1; off < 256; off <<= 1) {
    int v = (t >= off) ? p[t - off] : 0;
    __syncthreads();
    p[t] += v;
    __syncthreads();
  }
  if (ok) {
    row_start[idx] = partials[b] + p[t] - orig;
    counts[idx] = 0;  // becomes cursor for k_fill
  }
}

__global__ __launch_bounds__(256) void k_fill(const int* __restrict__ src,
                                              const int* __restrict__ dst,
                                              const float* __restrict__ att,
                                              const float* __restrict__ denom,
                                              const int* __restrict__ row_start,
                                              int* __restrict__ cursor,
                                              int2* __restrict__ bucket,
                                              int n_edges) {
  int i = blockIdx.x * blockDim.x + threadIdx.x;
  int stride = gridDim.x * blockDim.x;
  for (int e = i; e < n_edges; e += stride) {
    int d = dst[e], s = src[e];
    float w = att[e] / denom[s];
    int pos = atomicAdd(&cursor[d], 1);
    bucket[row_start[d] + pos] = make_int2(s, __float_as_int(w));
  }
}

__global__ __launch_bounds__(256) void k_agg(const uint4* __restrict__ hh4,
                                             const int* __restrict__ row_start,
                                             const int2* __restrict__ bucket,
                                             float* __restrict__ out, int n_nodes) {
  int lane = threadIdx.x & 63;
  int sub = lane >> 4, l16 = lane & 15;
  int d = blockIdx.x * 4 + (threadIdx.x >> 6);
  if (d >= n_nodes) return;
  int beg = row_start[d], end = row_start[d + 1];
  int cnt = end - beg;
  float a0 = 0.f, a1 = 0.f, a2 = 0.f, a3 = 0.f;
  float a4 = 0.f, a5 = 0.f, a6 = 0.f, a7 = 0.f;
  for (int base = 0; base < cnt; base += 64) {
    int nb = cnt - base; if (nb > 64) nb = 64;
    int2 ew = make_int2(0, 0);
    if (lane < nb) ew = bucket[beg + base + lane];
    int steps = (nb + 3) >> 2;
    for (int j = 0; j < steps; ++j) {
      int idx = j * 4 + sub;
      int s = __shfl(ew.x, idx);
      float w = __int_as_float(__shfl(ew.y, idx));
      if (idx < nb) {
        uint4 v = hh4[(size_t)s * 16 + l16];
        float2 f0 = unpack_f16(v.x), f1 = unpack_f16(v.y);
        float2 f2 = unpack_f16(v.z), f3 = unpack_f16(v.w);
        a0 = fmaf(w, f0.x, a0); a1 = fmaf(w, f0.y, a1);
        a2 = fmaf(w, f1.x, a2); a3 = fmaf(w, f1.y, a3);
        a4 = fmaf(w, f2.x, a4); a5 = fmaf(w, f2.y, a5);
        a6 = fmaf(w, f3.x, a6); a7 = fmaf(w, f3.y, a7);
      }
    }
  }
  #pragma unroll
  for (int off = 16; off < 64; off <<= 1) {
    a0 += __shfl_xor(a0, off); a1 += __shfl_xor(a1, off);
    a2 += __shfl_xor(a2, off); a3 += __shfl_xor(a3, off);
    a4 += __shfl_xor(a4, off); a5 += __shfl_xor(a5, off);
    a6 += __shfl_xor(a6, off); a7 += __shfl_xor(a7, off);
  }
  if (sub == 0) {
    *(float4*)&out[(size_t)d * 128 + l16 * 8]     = make_float4(a0, a1, a2, a3);
    *(float4*)&out[(size_t)d * 128 + l16 * 8 + 4] = make_float4(a4, a5, a6, a7);
  }
}

extern "C" void kernel_launch(void* const* d_in, const int* in_sizes, int n_in,
                              void* d_out, int out_size, void* d_ws, size_t ws_size,
                              hipStream_t stream) {
  const float* h   = (const float*)d_in[0];
  const int*   src = (const int*)d_in[1];
  const int*   dst = (const int*)d_in[2];
  const float* W1  = (const float*)d_in[3];
  const float* b1  = (const float*)d_in[4];
  const float* W2  = (const float*)d_in[5];
  const float* b2  = (const float*)d_in[6];
  float* out = (float*)d_out;

  int n_nodes = in_sizes[0] / 128;
  int n_edges = in_sizes[1];

  char* ws = (char*)d_ws;
  uint*   gh        = (uint*)ws;                            // n*64
  uint*   hh        = gh + (size_t)n_nodes * 64;            // n*64
  float*  att       = (float*)(hh + (size_t)n_nodes * 64);  // E
  float*  denom     = att + n_edges;                        // n
  int*    counts    = (int*)(denom + n_nodes);              // n (cursor later)
  int*    row_start = counts + n_nodes;                     // n+1
  int*    partials  = row_start + n_nodes + 1;              // 256
  ushort* w1t       = (ushort*)(partials + 256);            // 16384 (32 KiB)
  int2*   bucket    = (int2*)(((uintptr_t)(w1t + 16384) + 15) & ~(uintptr_t)15);

  hipMemsetAsync(denom, 0, (size_t)2 * n_nodes * sizeof(float), stream);

  int chunk = (n_nodes + 255) / 256;
  int n_tiles = (n_nodes + 15) / 16;
  k_transpose<<<64, 256, 0, stream>>>(W1, w1t);
  k_gemm <<<(n_tiles + 3) / 4, 256, 0, stream>>>(h, w1t, gh, (uint4*)hh, n_nodes);
  k_att  <<<2048, 256, 0, stream>>>((const uint4*)gh, src, dst, b1, W2, b2,
                                    att, denom, counts, n_edges);
  k_scanA<<<256, 256, 0, stream>>>(counts, partials, n_nodes, chunk);
  k_scanB<<<1, 256, 0, stream>>>(partials, row_start, n_nodes, n_edges);
  k_scanC<<<256, 256, 0, stream>>>(counts, partials, row_start, n_nodes, chunk);
  k_fill <<<2048, 256, 0, stream>>>(src, dst, att, denom, row_start, counts, bucket, n_edges);
  k_agg  <<<(n_nodes + 3) / 4, 256, 0, stream>>>((const uint4*)hh, row_start, bucket, out, n_nodes);
}